// Round 8
// baseline (533.308 us; speedup 1.0000x reference)
//
#include <hip/hip_runtime.h>
#include <hip/hip_bf16.h>

#define N_NODE 50000
#define NPAD   50048     // RSZ*NRANGE, padded per-rel node count for cnt/cur arrays
#define NEDGE  600000
#define NRANGE 128
#define RSZ    391       // ceil(N_NODE / NRANGE); 128*391 = 50048 >= 50000
#define CHUNK  4096
#define NBLK1  147       // ceil(NEDGE / CHUNK); last chunk = 2384 (divisible by 4)
#define GEMM_GX 391      // ceil(N_NODE / 128): 8-wave GEMM blocks

typedef __hip_bfloat16 bf16;
typedef __attribute__((ext_vector_type(8))) short short8;
typedef __attribute__((ext_vector_type(4))) float floatx4;

__device__ __forceinline__ short f2s(float f) {
    bf16 t = __float2bfloat16(f);
    return *(short*)&t;
}
__device__ __forceinline__ unsigned pk2(float lo, float hi) {
    return ((unsigned)(unsigned short)f2s(lo)) | (((unsigned)(unsigned short)f2s(hi)) << 16);
}
__device__ __forceinline__ void acc2(float& a, float& b, unsigned w, float m) {
    a += m * __uint_as_float(w << 16);
    b += m * __uint_as_float(w & 0xFFFF0000u);
}

// rel 0 = dd (dst=drug), 1 = gd (dst=drug), 2 = dg (dst=gene), 3 = gg (dst=gene)

// ---------- fused launch (512 thr): blocks [0,588) = degree histogram, [588,1370) = layer-1 GEMM ----------
// Direct-CSR step 1: per-edge global atomicAdd on cnt[rel][dst] (2.4M atomics over 200K
// addresses, ~12/addr — L2-parallel) + LDS-aggregated range sums rsum[512].
// Replaces the old 3-pass bucket partition; runs fully overlapped with GEMM1.
__global__ __launch_bounds__(512) void k_hist_gemm(
    const int* __restrict__ d0, const int* __restrict__ d1,
    const int* __restrict__ d2, const int* __restrict__ d3,
    int* __restrict__ rsum, int* __restrict__ cnt,
    const float* __restrict__ X0, const float* __restrict__ X1,
    const float* __restrict__ Wa0, const float* __restrict__ Wb0,
    const float* __restrict__ Wa1, const float* __restrict__ Wb1,
    bf16* __restrict__ out0, bf16* __restrict__ out1)
{
    __shared__ union {
        int hcur[NRANGE];
        short wl[4 * 8 * 512];   // 32 KB
    } u;

    int tid = threadIdx.x;
    if (blockIdx.x < 4 * NBLK1) {
        // ---------------- histogram path ----------------
        int bid = blockIdx.x;
        int rel = bid / NBLK1;
        int c   = bid - rel * NBLK1;
        const int* dp = rel == 0 ? d0 : rel == 1 ? d1 : rel == 2 ? d2 : d3;
        int e0 = c * CHUNK;
        int e1 = min(e0 + CHUNK, NEDGE);
        int nv = (e1 - e0) >> 2;           // both 4096 and 2384 divisible by 4
        const int4* dp4 = (const int4*)(dp + e0);
        int* cntr = cnt + rel * NPAD;

        if (tid < NRANGE) u.hcur[tid] = 0;
        __syncthreads();
        for (int i = tid; i < nv; i += 512) {
            int4 d = dp4[i];
            atomicAdd(&cntr[d.x], 1); atomicAdd(&u.hcur[d.x / RSZ], 1);
            atomicAdd(&cntr[d.y], 1); atomicAdd(&u.hcur[d.y / RSZ], 1);
            atomicAdd(&cntr[d.z], 1); atomicAdd(&u.hcur[d.z / RSZ], 1);
            atomicAdd(&cntr[d.w], 1); atomicAdd(&u.hcur[d.w / RSZ], 1);
        }
        __syncthreads();
        if (tid < NRANGE) {
            int v = u.hcur[tid];
            if (v) atomicAdd(&rsum[rel * NRANGE + tid], v);
        }
    } else {
        // ---------------- layer-1 GEMM path (K=128, NOUT=128, fp32 A), 8 waves ----------------
        constexpr int NB = 8, KC = 4, NH = 64;
        int bid2 = blockIdx.x - 4 * NBLK1;
        int sel  = bid2 >= GEMM_GX;
        int bx   = sel ? bid2 - GEMM_GX : bid2;
        const float* X  = sel ? X1 : X0;
        const float* Wa = sel ? Wa1 : Wa0;
        const float* Wb = sel ? Wb1 : Wb0;
        bf16*       outp = sel ? out1 : out0;

        for (int i = tid; i < KC * NB * 512; i += 512) {
            int j  = i & 7;
            int n  = (i >> 3) & 15;
            int q  = (i >> 7) & 3;
            int nb = (i >> 9) & (NB - 1);
            int kc = i >> 12;
            int k  = kc * 32 + q * 8 + j;
            int c  = nb * 16 + n;
            float w = (c < NH) ? Wa[k * NH + c] : Wb[k * NH + (c - NH)];
            u.wl[i] = f2s(w);
        }
        __syncthreads();

        int lane = tid & 63, wv = tid >> 6;        // wv in [0,8)
        int q = lane >> 4, lidx = lane & 15;
        int row0 = bx * 128 + wv * 16;
        int rowA = min(row0 + lidx, N_NODE - 1);

        floatx4 acc[NB];
#pragma unroll
        for (int nb = 0; nb < NB; nb++) acc[nb] = (floatx4){0.f, 0.f, 0.f, 0.f};

#pragma unroll
        for (int kc = 0; kc < KC; kc++) {
            const float* Xf = X + (size_t)rowA * 128 + kc * 32 + q * 8;
            float4 f0 = *(const float4*)Xf;
            float4 f1 = *(const float4*)(Xf + 4);
            short8 a;
            a[0] = f2s(f0.x); a[1] = f2s(f0.y); a[2] = f2s(f0.z); a[3] = f2s(f0.w);
            a[4] = f2s(f1.x); a[5] = f2s(f1.y); a[6] = f2s(f1.z); a[7] = f2s(f1.w);
#pragma unroll
            for (int nb = 0; nb < NB; nb++) {
                short8 b = *(const short8*)&u.wl[((kc * NB + nb) * 64 + lane) * 8];
                acc[nb] = __builtin_amdgcn_mfma_f32_16x16x32_bf16(a, b, acc[nb], 0, 0, 0);
            }
        }
#pragma unroll
        for (int nb = 0; nb < NB; nb++) {
#pragma unroll
            for (int r = 0; r < 4; r++) {
                int row = row0 + q * 4 + r;
                if (row < N_NODE)
                    outp[(size_t)row * 128 + nb * 16 + lidx] = __float2bfloat16(acc[nb][r]);
            }
        }
    }
}

// ---------- direct-CSR step 2: offsets. 512 tiny blocks, one per (rel,range). ----------
// rbase via local scan of rsum (proven pattern); 391-wide local scan of cnt; writes
// off (gather CSR) and cur (scatter cursors).
__global__ __launch_bounds__(512) void k_off(
    const int* __restrict__ rsum, const int* __restrict__ cnt,
    int* __restrict__ off, int* __restrict__ cur)
{
    __shared__ int sc[512];
    int bid = blockIdx.x;
    int rel = bid >> 7, r = bid & (NRANGE - 1);
    int tid = threadIdx.x;
    int range0 = r * RSZ;
    int RS = min(RSZ, N_NODE - range0);

    // rbase: exclusive scan of this rel's 128 range sums up to r
    int vb = (tid < NRANGE) ? rsum[rel * NRANGE + tid] : 0;
    sc[tid] = vb;
    __syncthreads();
    for (int d = 1; d < NRANGE; d <<= 1) {
        int t = (tid >= d && tid < NRANGE) ? sc[tid - d] : 0;
        __syncthreads();
        if (tid < NRANGE) sc[tid] += t;
        __syncthreads();
    }
    int rbase = (r > 0) ? sc[r - 1] : 0;
    __syncthreads();

    // local exclusive scan of 391 node counts (one element per thread)
    int x = (tid < RSZ) ? cnt[rel * NPAD + range0 + tid] : 0;
    sc[tid] = x;
    __syncthreads();
    for (int d = 1; d < 512; d <<= 1) {
        int t = (tid >= d) ? sc[tid - d] : 0;
        __syncthreads();
        sc[tid] += t;
        __syncthreads();
    }
    int excl = rbase + sc[tid] - x;
    if (tid < RSZ) cur[rel * NPAD + range0 + tid] = excl;
    if (tid < RS)  off[rel * (N_NODE + 1) + range0 + tid] = excl;
    if (r == NRANGE - 1 && tid == 0) off[rel * (N_NODE + 1) + N_NODE] = NEDGE;
}

// ---------- direct-CSR step 3: scatter edges via cursor atomics ----------
__global__ __launch_bounds__(512) void k_scatter(
    const int* __restrict__ d0, const int* __restrict__ s0,
    const int* __restrict__ d1, const int* __restrict__ s1,
    const int* __restrict__ d2, const int* __restrict__ s2,
    const int* __restrict__ d3, const int* __restrict__ s3,
    int* __restrict__ cur, unsigned short* __restrict__ edges)
{
    int bid = blockIdx.x;
    int rel = bid / NBLK1;
    int c   = bid - rel * NBLK1;
    const int* dp = rel == 0 ? d0 : rel == 1 ? d1 : rel == 2 ? d2 : d3;
    const int* sp = rel == 0 ? s0 : rel == 1 ? s1 : rel == 2 ? s2 : s3;
    int e0 = c * CHUNK;
    int e1 = min(e0 + CHUNK, NEDGE);
    int nv = (e1 - e0) >> 2;
    const int4* dp4 = (const int4*)(dp + e0);
    const int4* sp4 = (const int4*)(sp + e0);
    int* curr = cur + rel * NPAD;
    unsigned short* er = edges + (size_t)rel * NEDGE;

    for (int i = threadIdx.x; i < nv; i += 512) {
        int4 d = dp4[i];
        int4 s = sp4[i];
        int p0 = atomicAdd(&curr[d.x], 1); er[p0] = (unsigned short)s.x;
        int p1 = atomicAdd(&curr[d.y], 1); er[p1] = (unsigned short)s.y;
        int p2 = atomicAdd(&curr[d.z], 1); er[p2] = (unsigned short)s.z;
        int p3 = atomicAdd(&curr[d.w], 1); er[p3] = (unsigned short)s.w;
    }
}

// ---------- MFMA dual-weight GEMM pair (layer 2): out(bf16) = X @ [Wa | Wb] ----------
template <int K, int NOUT, bool AFP32>
__global__ __launch_bounds__(256) void k_gemm_pair(
    const void* __restrict__ X0, const void* __restrict__ X1,
    const float* __restrict__ Wa0, const float* __restrict__ Wb0,
    const float* __restrict__ Wa1, const float* __restrict__ Wb1,
    bf16* __restrict__ out0, bf16* __restrict__ out1, int M)
{
    constexpr int NB  = NOUT / 16;
    constexpr int KC  = K / 32;
    constexpr int NH  = NOUT / 2;
    constexpr int NBL = (NB == 8) ? 3 : 2;
    __shared__ short Wl[KC * NB * 512];

    int sel = blockIdx.y;
    const void*  X  = sel ? X1 : X0;
    const float* Wa = sel ? Wa1 : Wa0;
    const float* Wb = sel ? Wb1 : Wb0;
    bf16*        out = sel ? out1 : out0;

    int tid = threadIdx.x;
    for (int i = tid; i < KC * NB * 512; i += 256) {
        int j  = i & 7;
        int n  = (i >> 3) & 15;
        int q  = (i >> 7) & 3;
        int nb = (i >> 9) & (NB - 1);
        int kc = i >> (9 + NBL);
        int k  = kc * 32 + q * 8 + j;
        int c  = nb * 16 + n;
        float w = (c < NH) ? Wa[k * NH + c] : Wb[k * NH + (c - NH)];
        Wl[i] = f2s(w);
    }
    __syncthreads();

    int lane = tid & 63, wv = tid >> 6;
    int q = lane >> 4, lidx = lane & 15;
    int row0 = blockIdx.x * 64 + wv * 16;
    int rowA = min(row0 + lidx, M - 1);

    floatx4 acc[NB];
#pragma unroll
    for (int nb = 0; nb < NB; nb++) acc[nb] = (floatx4){0.f, 0.f, 0.f, 0.f};

#pragma unroll
    for (int kc = 0; kc < KC; kc++) {
        short8 a;
        if constexpr (AFP32) {
            const float* Xf = (const float*)X + (size_t)rowA * K + kc * 32 + q * 8;
            float4 f0 = *(const float4*)Xf;
            float4 f1 = *(const float4*)(Xf + 4);
            a[0] = f2s(f0.x); a[1] = f2s(f0.y); a[2] = f2s(f0.z); a[3] = f2s(f0.w);
            a[4] = f2s(f1.x); a[5] = f2s(f1.y); a[6] = f2s(f1.z); a[7] = f2s(f1.w);
        } else {
            a = *(const short8*)((const short*)X + (size_t)rowA * K + kc * 32 + q * 8);
        }
#pragma unroll
        for (int nb = 0; nb < NB; nb++) {
            short8 b = *(const short8*)&Wl[((kc * NB + nb) * 64 + lane) * 8];
            acc[nb] = __builtin_amdgcn_mfma_f32_16x16x32_bf16(a, b, acc[nb], 0, 0, 0);
        }
    }
#pragma unroll
    for (int nb = 0; nb < NB; nb++) {
#pragma unroll
        for (int r = 0; r < 4; r++) {
            int row = row0 + q * 4 + r;
            if (row < M)
                out[(size_t)row * NOUT + nb * 16 + lidx] = __float2bfloat16(acc[nb][r]);
        }
    }
}

// ---------- group-per-node segment accumulate (round-2 proven structure, u16 edges) ----------
template<int ROWU>
__device__ __forceinline__ void seg_run(
    int n, const unsigned short* __restrict__ ep, float sc,
    const unsigned* __restrict__ base, float* s)
{
    int nfull = n & ~3;
    for (int i = 0; i < nfull; i += 4) {
        int e0 = ep[i + 0];
        int e1 = ep[i + 1];
        int e2 = ep[i + 2];
        int e3 = ep[i + 3];
        uint4 w0 = *(const uint4*)(base + e0 * ROWU);
        uint4 w1 = *(const uint4*)(base + e1 * ROWU);
        uint4 w2 = *(const uint4*)(base + e2 * ROWU);
        uint4 w3 = *(const uint4*)(base + e3 * ROWU);
        acc2(s[0], s[1], w0.x, sc); acc2(s[2], s[3], w0.y, sc);
        acc2(s[4], s[5], w0.z, sc); acc2(s[6], s[7], w0.w, sc);
        acc2(s[0], s[1], w1.x, sc); acc2(s[2], s[3], w1.y, sc);
        acc2(s[4], s[5], w1.z, sc); acc2(s[6], s[7], w1.w, sc);
        acc2(s[0], s[1], w2.x, sc); acc2(s[2], s[3], w2.y, sc);
        acc2(s[4], s[5], w2.z, sc); acc2(s[6], s[7], w2.w, sc);
        acc2(s[0], s[1], w3.x, sc); acc2(s[2], s[3], w3.y, sc);
        acc2(s[4], s[5], w3.z, sc); acc2(s[6], s[7], w3.w, sc);
    }
    for (int i = nfull; i < n; i++) {
        int e = ep[i];
        uint4 w = *(const uint4*)(base + e * ROWU);
        acc2(s[0], s[1], w.x, sc); acc2(s[2], s[3], w.y, sc);
        acc2(s[4], s[5], w.z, sc); acc2(s[6], s[7], w.w, sc);
    }
}

// ---------- fused layer-1 gather: 8-lane group per node, 64 feats ----------
__global__ __launch_bounds__(256) void k_gather64v5(
    const bf16* __restrict__ m1,
    const int* __restrict__ offA0, const unsigned short* __restrict__ eA0,
    const int* __restrict__ offB0, const unsigned short* __restrict__ eB0,
    const float* __restrict__ bias0, bf16* __restrict__ out0,
    const int* __restrict__ offA1, const unsigned short* __restrict__ eA1,
    const int* __restrict__ offB1, const unsigned short* __restrict__ eB1,
    const float* __restrict__ bias1, bf16* __restrict__ out1)
{
    int tid  = threadIdx.x;
    int gid  = blockIdx.x * 32 + (tid >> 3);   // grid exact: 3125*32 = 100000
    int lidx = tid & 7;
    int half = (gid >= N_NODE);
    int wid  = gid - (half ? N_NODE : 0);
    const int* offA = half ? offA1 : offA0;
    const unsigned short* eA = half ? eA1 : eA0;
    const int* offB = half ? offB1 : offB0;
    const unsigned short* eB = half ? eB1 : eB0;
    const float* bias = half ? bias1 : bias0;
    bf16* out = half ? out1 : out0;

    const unsigned* base = (const unsigned*)m1 + (half ? 32 : 0) + lidx * 4;

    int begA = offA[wid], nA = offA[wid + 1] - begA;
    int begB = offB[wid], nB = offB[wid + 1] - begB;
    float ia = 1.f / (float)max(nA, 1);
    float ib = 1.f / (float)max(nB, 1);

    float s[8] = {0.f,0.f,0.f,0.f,0.f,0.f,0.f,0.f};
    seg_run<64>(nA, eA + begA, ia, base, s);
    seg_run<64>(nB, eB + begB, ib, base + N_NODE * 64, s);

    float h[8];
#pragma unroll
    for (int k = 0; k < 8; k++)
        h[k] = fmaxf(s[k] + bias[lidx * 8 + k], 0.f);
    uint4 v;
    v.x = pk2(h[0], h[1]); v.y = pk2(h[2], h[3]);
    v.z = pk2(h[4], h[5]); v.w = pk2(h[6], h[7]);
    *(uint4*)(out + (size_t)wid * 64 + lidx * 8) = v;
}

// ---------- fused layer-2 gather: 4-lane group per node, 32 feats, f32 out ----------
__global__ __launch_bounds__(256) void k_gather32v2(
    const bf16* __restrict__ m2,
    const int* __restrict__ offA0, const unsigned short* __restrict__ eA0,
    const int* __restrict__ offB0, const unsigned short* __restrict__ eB0,
    const float* __restrict__ bias0, float* __restrict__ out0,
    const int* __restrict__ offA1, const unsigned short* __restrict__ eA1,
    const int* __restrict__ offB1, const unsigned short* __restrict__ eB1,
    const float* __restrict__ bias1, float* __restrict__ out1)
{
    int tid  = threadIdx.x;
    int gid  = blockIdx.x * 64 + (tid >> 2);
    int lidx = tid & 3;
    if (gid >= 2 * N_NODE) return;
    int half = (gid >= N_NODE);
    int wid  = gid - (half ? N_NODE : 0);
    const int* offA = half ? offA1 : offA0;
    const unsigned short* eA = half ? eA1 : eA0;
    const int* offB = half ? offB1 : offB0;
    const unsigned short* eB = half ? eB1 : eB0;
    const float* bias = half ? bias1 : bias0;
    float* out = half ? out1 : out0;

    const unsigned* base = (const unsigned*)m2 + (half ? 16 : 0) + lidx * 4;

    int begA = offA[wid], nA = offA[wid + 1] - begA;
    int begB = offB[wid], nB = offB[wid + 1] - begB;
    float ia = 1.f / (float)max(nA, 1);
    float ib = 1.f / (float)max(nB, 1);

    float s[8] = {0.f,0.f,0.f,0.f,0.f,0.f,0.f,0.f};
    seg_run<32>(nA, eA + begA, ia, base, s);
    seg_run<32>(nB, eB + begB, ib, base + N_NODE * 32, s);

    float* o = out + (size_t)wid * 32 + lidx * 8;
    float4 v0, v1;
    v0.x = s[0] + bias[lidx * 8 + 0];
    v0.y = s[1] + bias[lidx * 8 + 1];
    v0.z = s[2] + bias[lidx * 8 + 2];
    v0.w = s[3] + bias[lidx * 8 + 3];
    v1.x = s[4] + bias[lidx * 8 + 4];
    v1.y = s[5] + bias[lidx * 8 + 5];
    v1.z = s[6] + bias[lidx * 8 + 6];
    v1.w = s[7] + bias[lidx * 8 + 7];
    *(float4*)o = v0;
    *(float4*)(o + 4) = v1;
}

// ---------------- launcher ----------------
extern "C" void kernel_launch(void* const* d_in, const int* in_sizes, int n_in,
                              void* d_out, int out_size, void* d_ws, size_t ws_size,
                              hipStream_t stream)
{
    const float* xd = (const float*)d_in[0];
    const float* xg = (const float*)d_in[1];
    const int* dd_src = (const int*)d_in[2];  const int* dd_dst = (const int*)d_in[3];
    const int* dg_src = (const int*)d_in[4];  const int* dg_dst = (const int*)d_in[5];
    const int* gd_src = (const int*)d_in[6];  const int* gd_dst = (const int*)d_in[7];
    const int* gg_src = (const int*)d_in[8];  const int* gg_dst = (const int*)d_in[9];
    const float* W1dd = (const float*)d_in[10];
    const float* W1dg = (const float*)d_in[11];
    const float* W1gd = (const float*)d_in[12];
    const float* W1gg = (const float*)d_in[13];
    const float* b1d  = (const float*)d_in[14];
    const float* b1g  = (const float*)d_in[15];
    const float* W2dd = (const float*)d_in[16];
    const float* W2dg = (const float*)d_in[17];
    const float* W2gd = (const float*)d_in[18];
    const float* W2gg = (const float*)d_in[19];
    const float* b2d  = (const float*)d_in[20];
    const float* b2g  = (const float*)d_in[21];
    float* out = (float*)d_out;

    // workspace layout (all 16B-aligned where vector-accessed; md1 byte offset
    // = 2048 + 2*800768 + 800016 + 4800000 = 7203600, divisible by 16)
    int* rsum = (int*)d_ws;                            // 512
    int* cnt  = rsum + 512;                            // 4*NPAD = 200192
    int* cur  = cnt + 4 * NPAD;                        // 4*NPAD
    int* off  = cur + 4 * NPAD;                        // 4*(N_NODE+1) = 200004
    unsigned short* edges = (unsigned short*)(off + 4 * (N_NODE + 1));  // 4*NEDGE u16 (4.8 MB)
    bf16* md1 = (bf16*)(edges + (size_t)4 * NEDGE);    // [md1|mg1]: 2*50000*128 bf16 (25.6 MB)
    bf16* mg1 = md1 + (size_t)N_NODE * 128;
    bf16* h   = mg1 + (size_t)N_NODE * 128;            // [hd|hg]: 2*50000*64 bf16 (12.8 MB)
    bf16* hd  = h;
    bf16* hg  = h + (size_t)N_NODE * 64;
    bf16* md2 = md1;                                   // layer-2 out packed (stride 64 bf16)
    bf16* mg2 = md1 + (size_t)N_NODE * 64;             // B-row i = row (i + N_NODE)

    // ---- stage 0: zero rsum + cnt (contiguous, 802816 B) ----
    hipMemsetAsync(rsum, 0, (512 + 4 * NPAD) * sizeof(int), stream);

    // ---- stage 1: degree histogram || layer-1 GEMM (one 512-thread launch) ----
    k_hist_gemm<<<4 * NBLK1 + 2 * GEMM_GX, 512, 0, stream>>>(
        dd_dst, gd_dst, dg_dst, gg_dst, rsum, cnt,
        xd, xg, W1dd, W1dg, W1gd, W1gg, md1, mg1);

    // ---- stage 2: offsets + cursors (512 tiny blocks) ----
    k_off<<<512, 512, 0, stream>>>(rsum, cnt, off, cur);

    // ---- stage 3: edge scatter via cursor atomics ----
    k_scatter<<<4 * NBLK1, 512, 0, stream>>>(
        dd_dst, dd_src, gd_dst, gd_src, dg_dst, dg_src, gg_dst, gg_src, cur, edges);

    const int* off_dd = off + 0 * (N_NODE + 1);
    const int* off_gd = off + 1 * (N_NODE + 1);
    const int* off_dg = off + 2 * (N_NODE + 1);
    const int* off_gg = off + 3 * (N_NODE + 1);
    const unsigned short* e_dd = edges + (size_t)0 * NEDGE;
    const unsigned short* e_gd = edges + (size_t)1 * NEDGE;
    const unsigned short* e_dg = edges + (size_t)2 * NEDGE;
    const unsigned short* e_gg = edges + (size_t)3 * NEDGE;

    int g64_grid = (2 * N_NODE) / 32;          // 3125 blocks exact
    int g32_grid = (2 * N_NODE + 63) / 64;     // 1563 blocks
    dim3 gemm2_grid((N_NODE + 63) / 64, 2);

    // ---- stage 4: layer-1 gather -> h ----
    k_gather64v5<<<g64_grid, 256, 0, stream>>>(
        md1,
        off_dd, e_dd, off_gd, e_gd, b1d, hd,
        off_dg, e_dg, off_gg, e_gg, b1g, hg);

    // ---- stage 5: layer-2 GEMM (md1 region is dead now) ----
    k_gemm_pair<64, 64, false><<<gemm2_grid, 256, 0, stream>>>(
        hd, hg, W2dd, W2dg, W2gd, W2gg, md2, mg2, N_NODE);

    // ---- stage 6: layer-2 gather -> out ----
    k_gather32v2<<<g32_grid, 256, 0, stream>>>(
        md2,
        off_dd, e_dd, off_gd, e_gd, b2d, out,
        off_dg, e_dg, off_gg, e_gg, b2g, out + (size_t)N_NODE * 32);
}

// Round 9
// 297.920 us; speedup vs baseline: 1.7901x; 1.7901x over previous
//
#include <hip/hip_runtime.h>
#include <hip/hip_bf16.h>

#define N_NODE 50000
#define NEDGE  600000
#define NRANGE 128
#define RSZ    391       // ceil(N_NODE / NRANGE); 128*391 = 50048 >= 50000
#define CAPB   6144      // slot capacity per (rel,range): mean 4688 + ~21 sigma
#define CHUNK  4096
#define NBLK1  147       // ceil(NEDGE / CHUNK); last chunk = 2384 (divisible by 4)
#define GEMM_GX 391      // ceil(N_NODE / 128): 8-wave GEMM blocks

typedef __hip_bfloat16 bf16;
typedef __attribute__((ext_vector_type(8))) short short8;
typedef __attribute__((ext_vector_type(4))) float floatx4;

__device__ __forceinline__ short f2s(float f) {
    bf16 t = __float2bfloat16(f);
    return *(short*)&t;
}
__device__ __forceinline__ unsigned pk2(float lo, float hi) {
    return ((unsigned)(unsigned short)f2s(lo)) | (((unsigned)(unsigned short)f2s(hi)) << 16);
}
__device__ __forceinline__ void acc2(float& a, float& b, unsigned w, float m) {
    a += m * __uint_as_float(w << 16);
    b += m * __uint_as_float(w & 0xFFFF0000u);
}

// rel 0 = dd (dst=drug), 1 = gd (dst=drug), 2 = dg (dst=gene), 3 = gg (dst=gene)
// key packing: (bucket:7 << 25) | (dst_local:9 << 16) | (src:16)

// ---------- fused launch (512 thr): blocks [0,588) = edge partition, [588,1370) = layer-1 GEMM ----------
// (round-7 proven form: int4 edge loads, 8-wave GEMM path)
__global__ __launch_bounds__(512) void k_part_gemm(
    const int* __restrict__ d0, const int* __restrict__ s0,
    const int* __restrict__ d1, const int* __restrict__ s1,
    const int* __restrict__ d2, const int* __restrict__ s2,
    const int* __restrict__ d3, const int* __restrict__ s3,
    int* __restrict__ gcur, unsigned* __restrict__ gpart,
    const float* __restrict__ X0, const float* __restrict__ X1,
    const float* __restrict__ Wa0, const float* __restrict__ Wb0,
    const float* __restrict__ Wa1, const float* __restrict__ Wb1,
    bf16* __restrict__ out0, bf16* __restrict__ out1)
{
    __shared__ union {
        struct { unsigned buf[CHUNK]; int sc[512]; int hcur[NRANGE]; int delta[NRANGE]; } p;
        short wl[4 * 8 * 512];   // 32 KB
    } u;

    int tid = threadIdx.x;
    if (blockIdx.x < 4 * NBLK1) {
        // ---------------- partition path ----------------
        int bid = blockIdx.x;
        int rel = bid / NBLK1;
        int c   = bid - rel * NBLK1;
        const int* dp = rel == 0 ? d0 : rel == 1 ? d1 : rel == 2 ? d2 : d3;
        const int* sp = rel == 0 ? s0 : rel == 1 ? s1 : rel == 2 ? s2 : s3;
        int e0 = c * CHUNK;
        int e1 = min(e0 + CHUNK, NEDGE);
        int cnt = e1 - e0;                 // 4096 or 2384; both divisible by 4
        const int4* dp4 = (const int4*)(dp + e0);
        const int4* sp4 = (const int4*)(sp + e0);
        int nv = cnt >> 2;

        if (tid < NRANGE) u.p.hcur[tid] = 0;
        __syncthreads();
        for (int i = tid; i < nv; i += 512) {
            int4 d = dp4[i];
            atomicAdd(&u.p.hcur[d.x / RSZ], 1);
            atomicAdd(&u.p.hcur[d.y / RSZ], 1);
            atomicAdd(&u.p.hcur[d.z / RSZ], 1);
            atomicAdd(&u.p.hcur[d.w / RSZ], 1);
        }
        __syncthreads();
        int v = (tid < NRANGE) ? u.p.hcur[tid] : 0;
        u.p.sc[tid] = v;
        __syncthreads();
        for (int d = 1; d < NRANGE; d <<= 1) {
            int t = (tid >= d && tid < NRANGE) ? u.p.sc[tid - d] : 0;
            __syncthreads();
            if (tid < NRANGE) u.p.sc[tid] += t;
            __syncthreads();
        }
        if (tid < NRANGE) {
            int start = u.p.sc[tid] - v;
            int bg    = rel * NRANGE + tid;
            int resv  = atomicAdd(&gcur[bg], v);
            u.p.delta[tid] = bg * CAPB + resv - start;
            u.p.hcur[tid]  = start;
        }
        __syncthreads();
        for (int i = tid; i < nv; i += 512) {
            int4 d = dp4[i];
            int4 s = sp4[i];
#define PUT(dd, ss) { int b = (dd) / RSZ; int p = atomicAdd(&u.p.hcur[b], 1); \
                      u.p.buf[p] = ((unsigned)b << 25) | ((unsigned)((dd) - b * RSZ) << 16) | (unsigned)(ss); }
            PUT(d.x, s.x) PUT(d.y, s.y) PUT(d.z, s.z) PUT(d.w, s.w)
#undef PUT
        }
        __syncthreads();
        for (int i = tid * 4; i < cnt; i += 2048) {
            uint4 kb = *(const uint4*)&u.p.buf[i];
            gpart[u.p.delta[kb.x >> 25] + i + 0] = kb.x;
            gpart[u.p.delta[kb.y >> 25] + i + 1] = kb.y;
            gpart[u.p.delta[kb.z >> 25] + i + 2] = kb.z;
            gpart[u.p.delta[kb.w >> 25] + i + 3] = kb.w;
        }
    } else {
        // ---------------- layer-1 GEMM path (K=128, NOUT=128, fp32 A), 8 waves ----------------
        constexpr int NB = 8, KC = 4, NH = 64;
        int bid2 = blockIdx.x - 4 * NBLK1;
        int sel  = bid2 >= GEMM_GX;
        int bx   = sel ? bid2 - GEMM_GX : bid2;
        const float* X  = sel ? X1 : X0;
        const float* Wa = sel ? Wa1 : Wa0;
        const float* Wb = sel ? Wb1 : Wb0;
        bf16*       outp = sel ? out1 : out0;

        for (int i = tid; i < KC * NB * 512; i += 512) {
            int j  = i & 7;
            int n  = (i >> 3) & 15;
            int q  = (i >> 7) & 3;
            int nb = (i >> 9) & (NB - 1);
            int kc = i >> 12;
            int k  = kc * 32 + q * 8 + j;
            int c  = nb * 16 + n;
            float w = (c < NH) ? Wa[k * NH + c] : Wb[k * NH + (c - NH)];
            u.wl[i] = f2s(w);
        }
        __syncthreads();

        int lane = tid & 63, wv = tid >> 6;        // wv in [0,8)
        int q = lane >> 4, lidx = lane & 15;
        int row0 = bx * 128 + wv * 16;
        int rowA = min(row0 + lidx, N_NODE - 1);

        floatx4 acc[NB];
#pragma unroll
        for (int nb = 0; nb < NB; nb++) acc[nb] = (floatx4){0.f, 0.f, 0.f, 0.f};

#pragma unroll
        for (int kc = 0; kc < KC; kc++) {
            const float* Xf = X + (size_t)rowA * 128 + kc * 32 + q * 8;
            float4 f0 = *(const float4*)Xf;
            float4 f1 = *(const float4*)(Xf + 4);
            short8 a;
            a[0] = f2s(f0.x); a[1] = f2s(f0.y); a[2] = f2s(f0.z); a[3] = f2s(f0.w);
            a[4] = f2s(f1.x); a[5] = f2s(f1.y); a[6] = f2s(f1.z); a[7] = f2s(f1.w);
#pragma unroll
            for (int nb = 0; nb < NB; nb++) {
                short8 b = *(const short8*)&u.wl[((kc * NB + nb) * 64 + lane) * 8];
                acc[nb] = __builtin_amdgcn_mfma_f32_16x16x32_bf16(a, b, acc[nb], 0, 0, 0);
            }
        }
#pragma unroll
        for (int nb = 0; nb < NB; nb++) {
#pragma unroll
            for (int r = 0; r < 4; r++) {
                int row = row0 + q * 4 + r;
                if (row < N_NODE)
                    outp[(size_t)row * 128 + nb * 16 + lidx] = __float2bfloat16(acc[nb][r]);
            }
        }
    }
}

// ---------- per (rel,range) block -> final CSR (512 thr, uint4 loads, local base scan) ----------
// (round-7 proven form)
__global__ __launch_bounds__(512) void k_csr(
    const unsigned* __restrict__ gpart, const int* __restrict__ gcnt,
    int* __restrict__ off, unsigned short* __restrict__ edges)
{
    __shared__ unsigned short stg[CAPB];   // first: 16B-aligned
    __shared__ int cur[RSZ];
    __shared__ int sc[512];
    int bid = blockIdx.x;
    int rel = bid >> 7, r = bid & (NRANGE - 1);
    int tid = threadIdx.x;
    int range0 = r * RSZ;
    int RS = min(RSZ, N_NODE - range0);
    if (RS < 0) RS = 0;
    int count = gcnt[bid];
    const uint4* gp4 = (const uint4*)(gpart + (size_t)bid * CAPB);
    const unsigned* gp = gpart + (size_t)bid * CAPB;
    int count4 = count & ~3;

    // local base: exclusive scan of this rel's 128 bucket counts up to r
    int vb = (tid < NRANGE) ? gcnt[rel * NRANGE + tid] : 0;
    sc[tid] = vb;
    __syncthreads();
    for (int d = 1; d < NRANGE; d <<= 1) {
        int t = (tid >= d && tid < NRANGE) ? sc[tid - d] : 0;
        __syncthreads();
        if (tid < NRANGE) sc[tid] += t;
        __syncthreads();
    }
    int base = (r > 0) ? sc[r - 1] : 0;
    __syncthreads();

    for (int i = tid; i < RSZ; i += 512) cur[i] = 0;
    __syncthreads();
    // hist (uint4)
    for (int i = tid * 4; i < count4; i += 2048) {
        uint4 g = gp4[i >> 2];
        atomicAdd(&cur[(g.x >> 16) & 0x1FF], 1);
        atomicAdd(&cur[(g.y >> 16) & 0x1FF], 1);
        atomicAdd(&cur[(g.z >> 16) & 0x1FF], 1);
        atomicAdd(&cur[(g.w >> 16) & 0x1FF], 1);
    }
    if (tid < (count & 3))
        atomicAdd(&cur[(gp[count4 + tid] >> 16) & 0x1FF], 1);
    __syncthreads();
    // exclusive scan of cur[0..RSZ), one slot per thread
    int x = (tid < RSZ) ? cur[tid] : 0;
    sc[tid] = x;
    __syncthreads();
    for (int d = 1; d < 512; d <<= 1) {
        int t = (tid >= d) ? sc[tid - d] : 0;
        __syncthreads();
        sc[tid] += t;
        __syncthreads();
    }
    int excl = sc[tid] - x;
    __syncthreads();
    if (tid < RSZ) cur[tid] = excl;
    __syncthreads();
    for (int i = tid; i < RS; i += 512)
        off[rel * (N_NODE + 1) + range0 + i] = base + cur[i];
    if (r == NRANGE - 1 && tid == 0) off[rel * (N_NODE + 1) + N_NODE] = NEDGE;
    __syncthreads();
    // scatter to stg (uint4)
    for (int i = tid * 4; i < count4; i += 2048) {
        uint4 g = gp4[i >> 2];
#define SCAT(gg) { int p = atomicAdd(&cur[((gg) >> 16) & 0x1FF], 1); stg[p] = (unsigned short)((gg) & 0xFFFFu); }
        SCAT(g.x) SCAT(g.y) SCAT(g.z) SCAT(g.w)
#undef SCAT
    }
    if (tid < (count & 3)) {
        unsigned g = gp[count4 + tid];
        int p = atomicAdd(&cur[(g >> 16) & 0x1FF], 1);
        stg[p] = (unsigned short)(g & 0xFFFFu);
    }
    __syncthreads();
    for (int i = tid; i < count; i += 512)
        edges[(size_t)rel * NEDGE + base + i] = stg[i];
}

// ---------- group-per-node segment accumulate (round-2 proven structure, u16 edges) ----------
template<int ROWU>
__device__ __forceinline__ void seg_run(
    int n, const unsigned short* __restrict__ ep, float sc,
    const unsigned* __restrict__ base, float* s)
{
    int nfull = n & ~3;
    for (int i = 0; i < nfull; i += 4) {
        int e0 = ep[i + 0];
        int e1 = ep[i + 1];
        int e2 = ep[i + 2];
        int e3 = ep[i + 3];
        uint4 w0 = *(const uint4*)(base + e0 * ROWU);
        uint4 w1 = *(const uint4*)(base + e1 * ROWU);
        uint4 w2 = *(const uint4*)(base + e2 * ROWU);
        uint4 w3 = *(const uint4*)(base + e3 * ROWU);
        acc2(s[0], s[1], w0.x, sc); acc2(s[2], s[3], w0.y, sc);
        acc2(s[4], s[5], w0.z, sc); acc2(s[6], s[7], w0.w, sc);
        acc2(s[0], s[1], w1.x, sc); acc2(s[2], s[3], w1.y, sc);
        acc2(s[4], s[5], w1.z, sc); acc2(s[6], s[7], w1.w, sc);
        acc2(s[0], s[1], w2.x, sc); acc2(s[2], s[3], w2.y, sc);
        acc2(s[4], s[5], w2.z, sc); acc2(s[6], s[7], w2.w, sc);
        acc2(s[0], s[1], w3.x, sc); acc2(s[2], s[3], w3.y, sc);
        acc2(s[4], s[5], w3.z, sc); acc2(s[6], s[7], w3.w, sc);
    }
    for (int i = nfull; i < n; i++) {
        int e = ep[i];
        uint4 w = *(const uint4*)(base + e * ROWU);
        acc2(s[0], s[1], w.x, sc); acc2(s[2], s[3], w.y, sc);
        acc2(s[4], s[5], w.z, sc); acc2(s[6], s[7], w.w, sc);
    }
}

// ---------- fused layer-1 gather + layer-2 transform ----------
// Phase 1 (per 8-lane group = one node): gather mean of m1 rows -> h (regs, bias+relu).
// Phase 2 (per block): h -> LDS, one barrier, 16 MFMAs compute m2 = h @ [W2a|W2b]
//   (replaces the separate gemm2 kernel + h global round-trip). 50000%32==16, so the
//   single drug/gene boundary block splits exactly at a 16-row MFMA tile; [md2|mg2]
//   contiguity makes the output address m2 + gid*64 for both halves.
__global__ __launch_bounds__(256) void k_gather64v6(
    const bf16* __restrict__ m1,
    const int* __restrict__ offA0, const unsigned short* __restrict__ eA0,
    const int* __restrict__ offB0, const unsigned short* __restrict__ eB0,
    const float* __restrict__ bias0,
    const int* __restrict__ offA1, const unsigned short* __restrict__ eA1,
    const int* __restrict__ offB1, const unsigned short* __restrict__ eB1,
    const float* __restrict__ bias1,
    const float* __restrict__ W2dd, const float* __restrict__ W2dg,
    const float* __restrict__ W2gd, const float* __restrict__ W2gg,
    bf16* __restrict__ m2)
{
    __shared__ short wd[4096];      // [W2dd|W2dg] as MFMA B-fragments (8 KB)
    __shared__ short wg[4096];      // [W2gd|W2gg]
    __shared__ short hlds[32 * 64]; // block's 32 h-rows, bf16 (4 KB)

    int tid  = threadIdx.x;

    // ---- stage W2 B-fragments (same layout as k_gemm_pair<64,64> staging) ----
    for (int i = tid; i < 4096; i += 256) {
        int j  = i & 7;
        int n  = (i >> 3) & 15;
        int q  = (i >> 7) & 3;
        int nb = (i >> 9) & 3;
        int kc = i >> 11;
        int k  = kc * 32 + q * 8 + j;
        int c  = nb * 16 + n;
        float w0 = (c < 32) ? W2dd[k * 32 + c] : W2dg[k * 32 + (c - 32)];
        float w1 = (c < 32) ? W2gd[k * 32 + c] : W2gg[k * 32 + (c - 32)];
        wd[i] = f2s(w0);
        wg[i] = f2s(w1);
    }
    // (no barrier yet: wd/wg not read until the barrier below)

    // ---- phase 1: gather (round-7 proven structure) ----
    int gid  = blockIdx.x * 32 + (tid >> 3);   // grid exact: 3125*32 = 100000
    int lidx = tid & 7;
    int half = (gid >= N_NODE);
    int wid  = gid - (half ? N_NODE : 0);
    const int* offA = half ? offA1 : offA0;
    const unsigned short* eA = half ? eA1 : eA0;
    const int* offB = half ? offB1 : offB0;
    const unsigned short* eB = half ? eB1 : eB0;
    const float* bias = half ? bias1 : bias0;

    const unsigned* base = (const unsigned*)m1 + (half ? 32 : 0) + lidx * 4;

    int begA = offA[wid], nA = offA[wid + 1] - begA;
    int begB = offB[wid], nB = offB[wid + 1] - begB;
    float ia = 1.f / (float)max(nA, 1);
    float ib = 1.f / (float)max(nB, 1);

    float s[8] = {0.f,0.f,0.f,0.f,0.f,0.f,0.f,0.f};
    seg_run<64>(nA, eA + begA, ia, base, s);
    seg_run<64>(nB, eB + begB, ib, base + N_NODE * 64, s);

    float h[8];
#pragma unroll
    for (int k = 0; k < 8; k++)
        h[k] = fmaxf(s[k] + bias[lidx * 8 + k], 0.f);
    uint4 v;
    v.x = pk2(h[0], h[1]); v.y = pk2(h[2], h[3]);
    v.z = pk2(h[4], h[5]); v.w = pk2(h[6], h[7]);
    *(uint4*)&hlds[(tid >> 3) * 64 + lidx * 8] = v;
    __syncthreads();

    // ---- phase 2: MFMA transform. wave wv -> row-tile rt = wv>>1, col-tiles nb0, nb0+1 ----
    int wv = tid >> 6, lane = tid & 63;
    int q = lane >> 4, l16 = lane & 15;
    int rt = wv >> 1;
    int hrow = (blockIdx.x * 32 + rt * 16) >= N_NODE;   // per-tile half (tile-aligned boundary)
    const short* wsel = hrow ? wg : wd;
    int nb0 = (wv & 1) * 2, nb1 = nb0 + 1;

    floatx4 acc0 = (floatx4){0.f,0.f,0.f,0.f};
    floatx4 acc1 = (floatx4){0.f,0.f,0.f,0.f};
#pragma unroll
    for (int kc = 0; kc < 2; kc++) {
        short8 a  = *(const short8*)&hlds[(rt * 16 + l16) * 64 + kc * 32 + q * 8];
        short8 b0 = *(const short8*)&wsel[((kc * 4 + nb0) * 64 + lane) * 8];
        short8 b1 = *(const short8*)&wsel[((kc * 4 + nb1) * 64 + lane) * 8];
        acc0 = __builtin_amdgcn_mfma_f32_16x16x32_bf16(a, b0, acc0, 0, 0, 0);
        acc1 = __builtin_amdgcn_mfma_f32_16x16x32_bf16(a, b1, acc1, 0, 0, 0);
    }
#pragma unroll
    for (int r = 0; r < 4; r++) {
        int row = rt * 16 + q * 4 + r;                 // within block
        bf16* o = m2 + ((size_t)blockIdx.x * 32 + row) * 64;
        o[nb0 * 16 + l16] = __float2bfloat16(acc0[r]);
        o[nb1 * 16 + l16] = __float2bfloat16(acc1[r]);
    }
}

// ---------- fused layer-2 gather: 4-lane group per node, 32 feats, f32 out ----------
// (round-2/7 proven form; m2 = [md2|mg2] stride 32 uints, B via base + N_NODE*32)
__global__ __launch_bounds__(256) void k_gather32v2(
    const bf16* __restrict__ m2,
    const int* __restrict__ offA0, const unsigned short* __restrict__ eA0,
    const int* __restrict__ offB0, const unsigned short* __restrict__ eB0,
    const float* __restrict__ bias0, float* __restrict__ out0,
    const int* __restrict__ offA1, const unsigned short* __restrict__ eA1,
    const int* __restrict__ offB1, const unsigned short* __restrict__ eB1,
    const float* __restrict__ bias1, float* __restrict__ out1)
{
    int tid  = threadIdx.x;
    int gid  = blockIdx.x * 64 + (tid >> 2);
    int lidx = tid & 3;
    if (gid >= 2 * N_NODE) return;
    int half = (gid >= N_NODE);
    int wid  = gid - (half ? N_NODE : 0);
    const int* offA = half ? offA1 : offA0;
    const unsigned short* eA = half ? eA1 : eA0;
    const int* offB = half ? offB1 : offB0;
    const unsigned short* eB = half ? eB1 : eB0;
    const float* bias = half ? bias1 : bias0;
    float* out = half ? out1 : out0;

    const unsigned* base = (const unsigned*)m2 + (half ? 16 : 0) + lidx * 4;

    int begA = offA[wid], nA = offA[wid + 1] - begA;
    int begB = offB[wid], nB = offB[wid + 1] - begB;
    float ia = 1.f / (float)max(nA, 1);
    float ib = 1.f / (float)max(nB, 1);

    float s[8] = {0.f,0.f,0.f,0.f,0.f,0.f,0.f,0.f};
    seg_run<32>(nA, eA + begA, ia, base, s);
    seg_run<32>(nB, eB + begB, ib, base + N_NODE * 32, s);

    float* o = out + (size_t)wid * 32 + lidx * 8;
    float4 v0, v1;
    v0.x = s[0] + bias[lidx * 8 + 0];
    v0.y = s[1] + bias[lidx * 8 + 1];
    v0.z = s[2] + bias[lidx * 8 + 2];
    v0.w = s[3] + bias[lidx * 8 + 3];
    v1.x = s[4] + bias[lidx * 8 + 4];
    v1.y = s[5] + bias[lidx * 8 + 5];
    v1.z = s[6] + bias[lidx * 8 + 6];
    v1.w = s[7] + bias[lidx * 8 + 7];
    *(float4*)o = v0;
    *(float4*)(o + 4) = v1;
}

// ---------------- launcher ----------------
extern "C" void kernel_launch(void* const* d_in, const int* in_sizes, int n_in,
                              void* d_out, int out_size, void* d_ws, size_t ws_size,
                              hipStream_t stream)
{
    const float* xd = (const float*)d_in[0];
    const float* xg = (const float*)d_in[1];
    const int* dd_src = (const int*)d_in[2];  const int* dd_dst = (const int*)d_in[3];
    const int* dg_src = (const int*)d_in[4];  const int* dg_dst = (const int*)d_in[5];
    const int* gd_src = (const int*)d_in[6];  const int* gd_dst = (const int*)d_in[7];
    const int* gg_src = (const int*)d_in[8];  const int* gg_dst = (const int*)d_in[9];
    const float* W1dd = (const float*)d_in[10];
    const float* W1dg = (const float*)d_in[11];
    const float* W1gd = (const float*)d_in[12];
    const float* W1gg = (const float*)d_in[13];
    const float* b1d  = (const float*)d_in[14];
    const float* b1g  = (const float*)d_in[15];
    const float* W2dd = (const float*)d_in[16];
    const float* W2dg = (const float*)d_in[17];
    const float* W2gd = (const float*)d_in[18];
    const float* W2gg = (const float*)d_in[19];
    const float* b2d  = (const float*)d_in[20];
    const float* b2g  = (const float*)d_in[21];
    float* out = (float*)d_out;

    // workspace layout (all vector-accessed regions 16B-aligned)
    int* gcur     = (int*)d_ws;                        // 512 ints
    int* off      = gcur + 512;                        // 4*(N_NODE+1) = 200004
    unsigned short* edges = (unsigned short*)(off + 4 * (N_NODE + 1));  // 4*NEDGE u16 (4.8 MB)
    bf16* md1     = (bf16*)(edges + (size_t)4 * NEDGE);// [md1|mg1]: 2*50000*128 bf16 (25.6 MB)
    bf16* mg1     = md1 + (size_t)N_NODE * 128;
    bf16* m2      = mg1 + (size_t)N_NODE * 128;        // [md2|mg2]: 2*50000*64 bf16 (12.8 MB)
    unsigned* gpart = (unsigned*)m2;                   // 512*CAPB uints (12.58 MB) aliases m2:
                                                       // dead after k_csr, before gather64 writes m2.
                                                       // (md1 must NOT alias gpart: GEMM runs || part.)

    // ---- stage 1: edge partition || layer-1 GEMM (one 512-thread launch) ----
    hipMemsetAsync(gcur, 0, 512 * sizeof(int), stream);
    k_part_gemm<<<4 * NBLK1 + 2 * GEMM_GX, 512, 0, stream>>>(
        dd_dst, dd_src, gd_dst, gd_src, dg_dst, dg_src, gg_dst, gg_src, gcur, gpart,
        xd, xg, W1dd, W1dg, W1gd, W1gg, md1, mg1);

    // ---- stage 2: CSR finalize ----
    k_csr<<<512, 512, 0, stream>>>(gpart, gcur, off, edges);

    const int* off_dd = off + 0 * (N_NODE + 1);
    const int* off_gd = off + 1 * (N_NODE + 1);
    const int* off_dg = off + 2 * (N_NODE + 1);
    const int* off_gg = off + 3 * (N_NODE + 1);
    const unsigned short* e_dd = edges + (size_t)0 * NEDGE;
    const unsigned short* e_gd = edges + (size_t)1 * NEDGE;
    const unsigned short* e_dg = edges + (size_t)2 * NEDGE;
    const unsigned short* e_gg = edges + (size_t)3 * NEDGE;

    int g64_grid = (2 * N_NODE) / 32;          // 3125 blocks exact
    int g32_grid = (2 * N_NODE + 63) / 64;     // 1563 blocks

    // ---- stage 3: layer-1 gather + fused layer-2 transform -> m2 ----
    k_gather64v6<<<g64_grid, 256, 0, stream>>>(
        md1,
        off_dd, e_dd, off_gd, e_gd, b1d,
        off_dg, e_dg, off_gg, e_gg, b1g,
        W2dd, W2dg, W2gd, W2gg, m2);

    // ---- stage 4: layer-2 gather -> out ----
    k_gather32v2<<<g32_grid, 256, 0, stream>>>(
        m2,
        off_dd, e_dd, off_gd, e_gd, b2d, out,
        off_dg, e_dg, off_gg, e_gg, b2g, out + (size_t)N_NODE * 32);
}

// Round 10
// 291.803 us; speedup vs baseline: 1.8276x; 1.0210x over previous
//
#include <hip/hip_runtime.h>
#include <hip/hip_bf16.h>

#define N_NODE 50000
#define NEDGE  600000
#define NRANGE 128
#define RSZ    391       // ceil(N_NODE / NRANGE); 128*391 = 50048 >= 50000
#define CAPB   6144      // slot capacity per (rel,range): mean 4688 + ~21 sigma
#define CHUNK  8192
#define NBLK1  74        // ceil(NEDGE / CHUNK); last chunk = 1984 (divisible by 4)
#define GEMM_GB 196      // GEMM blocks per problem; each does 2 row-tiles of 128

typedef __hip_bfloat16 bf16;
typedef __attribute__((ext_vector_type(8))) short short8;
typedef __attribute__((ext_vector_type(4))) float floatx4;

__device__ __forceinline__ short f2s(float f) {
    bf16 t = __float2bfloat16(f);
    return *(short*)&t;
}
__device__ __forceinline__ unsigned pk2(float lo, float hi) {
    return ((unsigned)(unsigned short)f2s(lo)) | (((unsigned)(unsigned short)f2s(hi)) << 16);
}
__device__ __forceinline__ void acc2(float& a, float& b, unsigned w, float m) {
    a += m * __uint_as_float(w << 16);
    b += m * __uint_as_float(w & 0xFFFF0000u);
}
// wave-inclusive scan (64 lanes), Kogge-Stone via shfl_up
__device__ __forceinline__ int wscan(int x, int lane) {
#pragma unroll
    for (int d = 1; d < 64; d <<= 1) {
        int t = __shfl_up(x, d);
        if (lane >= d) x += t;
    }
    return x;
}

// rel 0 = dd (dst=drug), 1 = gd (dst=drug), 2 = dg (dst=gene), 3 = gg (dst=gene)
// key packing: (bucket:7 << 25) | (dst_local:9 << 16) | (src:16)

// ---------- fused launch (512 thr): blocks [0,296) = edge partition, [296,688) = layer-1 GEMM ----------
// 688 blocks <= 1024 residency (4/CU) -> single scheduling round. Shfl scans (1 barrier).
__global__ __launch_bounds__(512) void k_part_gemm(
    const int* __restrict__ d0, const int* __restrict__ s0,
    const int* __restrict__ d1, const int* __restrict__ s1,
    const int* __restrict__ d2, const int* __restrict__ s2,
    const int* __restrict__ d3, const int* __restrict__ s3,
    int* __restrict__ gcur, unsigned* __restrict__ gpart,
    const float* __restrict__ X0, const float* __restrict__ X1,
    const float* __restrict__ Wa0, const float* __restrict__ Wb0,
    const float* __restrict__ Wa1, const float* __restrict__ Wb1,
    bf16* __restrict__ out0, bf16* __restrict__ out1)
{
    __shared__ union {
        struct { unsigned buf[CHUNK]; int hcur[NRANGE]; int delta[NRANGE]; int wsum[2]; } p;
        short wl[4 * 8 * 512];   // 32 KB
    } u;

    int tid = threadIdx.x;
    if (blockIdx.x < 4 * NBLK1) {
        // ---------------- partition path (8192-edge chunks) ----------------
        int bid = blockIdx.x;
        int rel = bid / NBLK1;
        int c   = bid - rel * NBLK1;
        const int* dp = rel == 0 ? d0 : rel == 1 ? d1 : rel == 2 ? d2 : d3;
        const int* sp = rel == 0 ? s0 : rel == 1 ? s1 : rel == 2 ? s2 : s3;
        int e0 = c * CHUNK;
        int e1 = min(e0 + CHUNK, NEDGE);
        int cnt = e1 - e0;                 // 8192 or 1984; both divisible by 4
        const int4* dp4 = (const int4*)(dp + e0);
        const int4* sp4 = (const int4*)(sp + e0);
        int nv = cnt >> 2;

        if (tid < NRANGE) u.p.hcur[tid] = 0;
        __syncthreads();
        // pass 1: bucket counts (int4 loads, LDS atomics)
        for (int i = tid; i < nv; i += 512) {
            int4 d = dp4[i];
            atomicAdd(&u.p.hcur[d.x / RSZ], 1);
            atomicAdd(&u.p.hcur[d.y / RSZ], 1);
            atomicAdd(&u.p.hcur[d.z / RSZ], 1);
            atomicAdd(&u.p.hcur[d.w / RSZ], 1);
        }
        __syncthreads();
        // 128-wide exclusive scan via 2-wave shfl scan (1 barrier)
        int lane = tid & 63, wv6 = tid >> 6;
        int v = (tid < NRANGE) ? u.p.hcur[tid] : 0;
        int inc = wscan(v, lane);
        if (lane == 63 && wv6 < 2) u.p.wsum[wv6] = inc;
        __syncthreads();
        if (tid < NRANGE) {
            int incl  = inc + ((wv6 == 1) ? u.p.wsum[0] : 0);
            int start = incl - v;
            int bg    = rel * NRANGE + tid;
            int resv  = atomicAdd(&gcur[bg], v);
            u.p.delta[tid] = bg * CAPB + resv - start;
            u.p.hcur[tid]  = start;
        }
        __syncthreads();
        // pass 2: fill buf bucketed
        for (int i = tid; i < nv; i += 512) {
            int4 d = dp4[i];
            int4 s = sp4[i];
#define PUT(dd, ss) { int b = (dd) / RSZ; int p = atomicAdd(&u.p.hcur[b], 1); \
                      u.p.buf[p] = ((unsigned)b << 25) | ((unsigned)((dd) - b * RSZ) << 16) | (unsigned)(ss); }
            PUT(d.x, s.x) PUT(d.y, s.y) PUT(d.z, s.z) PUT(d.w, s.w)
#undef PUT
        }
        __syncthreads();
        // pass 3: scatter to global slots
        for (int i = tid * 4; i < cnt; i += 2048) {
            uint4 kb = *(const uint4*)&u.p.buf[i];
            gpart[u.p.delta[kb.x >> 25] + i + 0] = kb.x;
            gpart[u.p.delta[kb.y >> 25] + i + 1] = kb.y;
            gpart[u.p.delta[kb.z >> 25] + i + 2] = kb.z;
            gpart[u.p.delta[kb.w >> 25] + i + 3] = kb.w;
        }
    } else {
        // ---------------- layer-1 GEMM path: 2 row-tiles of 128 per block, 8 waves ----------------
        constexpr int NB = 8, KC = 4, NH = 64;
        int bid2 = blockIdx.x - 4 * NBLK1;         // 0..391
        int sel  = bid2 >= GEMM_GB;
        int bx   = sel ? bid2 - GEMM_GB : bid2;
        const float* X  = sel ? X1 : X0;
        const float* Wa = sel ? Wa1 : Wa0;
        const float* Wb = sel ? Wb1 : Wb0;
        bf16*       outp = sel ? out1 : out0;

        for (int i = tid; i < KC * NB * 512; i += 512) {
            int j  = i & 7;
            int n  = (i >> 3) & 15;
            int q  = (i >> 7) & 3;
            int nb = (i >> 9) & (NB - 1);
            int kc = i >> 12;
            int k  = kc * 32 + q * 8 + j;
            int c  = nb * 16 + n;
            float w = (c < NH) ? Wa[k * NH + c] : Wb[k * NH + (c - NH)];
            u.wl[i] = f2s(w);
        }
        __syncthreads();

        int lane = tid & 63, wv = tid >> 6;        // wv in [0,8)
        int q = lane >> 4, lidx = lane & 15;

#pragma unroll
        for (int t = 0; t < 2; t++) {
            int tile = bx * 2 + t;
            if (tile * 128 >= N_NODE) break;       // dead tail tile (tile 391)
            int row0 = tile * 128 + wv * 16;
            int rowA = min(row0 + lidx, N_NODE - 1);

            floatx4 acc[NB];
#pragma unroll
            for (int nb = 0; nb < NB; nb++) acc[nb] = (floatx4){0.f, 0.f, 0.f, 0.f};

#pragma unroll
            for (int kc = 0; kc < KC; kc++) {
                const float* Xf = X + (size_t)rowA * 128 + kc * 32 + q * 8;
                float4 f0 = *(const float4*)Xf;
                float4 f1 = *(const float4*)(Xf + 4);
                short8 a;
                a[0] = f2s(f0.x); a[1] = f2s(f0.y); a[2] = f2s(f0.z); a[3] = f2s(f0.w);
                a[4] = f2s(f1.x); a[5] = f2s(f1.y); a[6] = f2s(f1.z); a[7] = f2s(f1.w);
#pragma unroll
                for (int nb = 0; nb < NB; nb++) {
                    short8 b = *(const short8*)&u.wl[((kc * NB + nb) * 64 + lane) * 8];
                    acc[nb] = __builtin_amdgcn_mfma_f32_16x16x32_bf16(a, b, acc[nb], 0, 0, 0);
                }
            }
#pragma unroll
            for (int nb = 0; nb < NB; nb++) {
#pragma unroll
                for (int r = 0; r < 4; r++) {
                    int row = row0 + q * 4 + r;
                    if (row < N_NODE)
                        outp[(size_t)row * 128 + nb * 16 + lidx] = __float2bfloat16(acc[nb][r]);
                }
            }
        }
    }
}

// ---------- per (rel,range) block -> final CSR (512 thr, uint4 loads, shfl scans) ----------
__global__ __launch_bounds__(512) void k_csr(
    const unsigned* __restrict__ gpart, const int* __restrict__ gcnt,
    int* __restrict__ off, unsigned short* __restrict__ edges)
{
    __shared__ unsigned short stg[CAPB];   // first: 16B-aligned
    __shared__ int cur[RSZ];
    __shared__ int wsum[8];
    int bid = blockIdx.x;
    int rel = bid >> 7, r = bid & (NRANGE - 1);
    int tid = threadIdx.x;
    int lane = tid & 63, wv = tid >> 6;
    int range0 = r * RSZ;
    int RS = min(RSZ, N_NODE - range0);
    if (RS < 0) RS = 0;
    int count = gcnt[bid];
    const uint4* gp4 = (const uint4*)(gpart + (size_t)bid * CAPB);
    const unsigned* gp = gpart + (size_t)bid * CAPB;
    int count4 = count & ~3;

    // base = sum of gcnt[rel*128 + i] for i < r : masked 2-wave reduction (1 barrier)
    int vb = (tid < r) ? gcnt[rel * NRANGE + tid] : 0;   // tid<r implies tid<128
#pragma unroll
    for (int d = 32; d; d >>= 1) vb += __shfl_xor(vb, d);
    if (lane == 0 && wv < 2) wsum[wv] = vb;
    for (int i = tid; i < RSZ; i += 512) cur[i] = 0;
    __syncthreads();
    int base = wsum[0] + wsum[1];

    // hist (uint4)
    for (int i = tid * 4; i < count4; i += 2048) {
        uint4 g = gp4[i >> 2];
        atomicAdd(&cur[(g.x >> 16) & 0x1FF], 1);
        atomicAdd(&cur[(g.y >> 16) & 0x1FF], 1);
        atomicAdd(&cur[(g.z >> 16) & 0x1FF], 1);
        atomicAdd(&cur[(g.w >> 16) & 0x1FF], 1);
    }
    if (tid < (count & 3))
        atomicAdd(&cur[(gp[count4 + tid] >> 16) & 0x1FF], 1);
    __syncthreads();

    // 391-wide exclusive scan via 8-wave shfl scan (2 barriers)
    int x = (tid < RSZ) ? cur[tid] : 0;
    int inc = wscan(x, lane);
    if (lane == 63) wsum[wv] = inc;
    __syncthreads();
    int pre = 0;
#pragma unroll
    for (int w = 0; w < 7; w++) pre += (w < wv) ? wsum[w] : 0;
    int excl = inc + pre - x;
    if (tid < RSZ) cur[tid] = excl;
    __syncthreads();

    if (tid < RS)
        off[rel * (N_NODE + 1) + range0 + tid] = base + cur[tid];
    if (r == NRANGE - 1 && tid == 0) off[rel * (N_NODE + 1) + N_NODE] = NEDGE;
    // no barrier needed: off written from cur[tid] (own slot), scatter uses atomics on cur

    // scatter to stg (uint4)
    for (int i = tid * 4; i < count4; i += 2048) {
        uint4 g = gp4[i >> 2];
#define SCAT(gg) { int p = atomicAdd(&cur[((gg) >> 16) & 0x1FF], 1); stg[p] = (unsigned short)((gg) & 0xFFFFu); }
        SCAT(g.x) SCAT(g.y) SCAT(g.z) SCAT(g.w)
#undef SCAT
    }
    if (tid < (count & 3)) {
        unsigned g = gp[count4 + tid];
        int p = atomicAdd(&cur[(g >> 16) & 0x1FF], 1);
        stg[p] = (unsigned short)(g & 0xFFFFu);
    }
    __syncthreads();
    for (int i = tid; i < count; i += 512)
        edges[(size_t)rel * NEDGE + base + i] = stg[i];
}

// ---------- MFMA dual-weight GEMM pair (layer 2): out(bf16) = X @ [Wa | Wb] ----------
template <int K, int NOUT, bool AFP32>
__global__ __launch_bounds__(256) void k_gemm_pair(
    const void* __restrict__ X0, const void* __restrict__ X1,
    const float* __restrict__ Wa0, const float* __restrict__ Wb0,
    const float* __restrict__ Wa1, const float* __restrict__ Wb1,
    bf16* __restrict__ out0, bf16* __restrict__ out1, int M)
{
    constexpr int NB  = NOUT / 16;
    constexpr int KC  = K / 32;
    constexpr int NH  = NOUT / 2;
    constexpr int NBL = (NB == 8) ? 3 : 2;
    __shared__ short Wl[KC * NB * 512];

    int sel = blockIdx.y;
    const void*  X  = sel ? X1 : X0;
    const float* Wa = sel ? Wa1 : Wa0;
    const float* Wb = sel ? Wb1 : Wb0;
    bf16*        out = sel ? out1 : out0;

    int tid = threadIdx.x;
    for (int i = tid; i < KC * NB * 512; i += 256) {
        int j  = i & 7;
        int n  = (i >> 3) & 15;
        int q  = (i >> 7) & 3;
        int nb = (i >> 9) & (NB - 1);
        int kc = i >> (9 + NBL);
        int k  = kc * 32 + q * 8 + j;
        int c  = nb * 16 + n;
        float w = (c < NH) ? Wa[k * NH + c] : Wb[k * NH + (c - NH)];
        Wl[i] = f2s(w);
    }
    __syncthreads();

    int lane = tid & 63, wv = tid >> 6;
    int q = lane >> 4, lidx = lane & 15;
    int row0 = blockIdx.x * 64 + wv * 16;
    int rowA = min(row0 + lidx, M - 1);

    floatx4 acc[NB];
#pragma unroll
    for (int nb = 0; nb < NB; nb++) acc[nb] = (floatx4){0.f, 0.f, 0.f, 0.f};

#pragma unroll
    for (int kc = 0; kc < KC; kc++) {
        short8 a;
        if constexpr (AFP32) {
            const float* Xf = (const float*)X + (size_t)rowA * K + kc * 32 + q * 8;
            float4 f0 = *(const float4*)Xf;
            float4 f1 = *(const float4*)(Xf + 4);
            a[0] = f2s(f0.x); a[1] = f2s(f0.y); a[2] = f2s(f0.z); a[3] = f2s(f0.w);
            a[4] = f2s(f1.x); a[5] = f2s(f1.y); a[6] = f2s(f1.z); a[7] = f2s(f1.w);
        } else {
            a = *(const short8*)((const short*)X + (size_t)rowA * K + kc * 32 + q * 8);
        }
#pragma unroll
        for (int nb = 0; nb < NB; nb++) {
            short8 b = *(const short8*)&Wl[((kc * NB + nb) * 64 + lane) * 8];
            acc[nb] = __builtin_amdgcn_mfma_f32_16x16x32_bf16(a, b, acc[nb], 0, 0, 0);
        }
    }
#pragma unroll
    for (int nb = 0; nb < NB; nb++) {
#pragma unroll
        for (int r = 0; r < 4; r++) {
            int row = row0 + q * 4 + r;
            if (row < M)
                out[(size_t)row * NOUT + nb * 16 + lidx] = __float2bfloat16(acc[nb][r]);
        }
    }
}

// ---------- group-per-node segment accumulate (round-2 proven structure, u16 edges) ----------
template<int ROWU>
__device__ __forceinline__ void seg_run(
    int n, const unsigned short* __restrict__ ep, float sc,
    const unsigned* __restrict__ base, float* s)
{
    int nfull = n & ~3;
    for (int i = 0; i < nfull; i += 4) {
        int e0 = ep[i + 0];
        int e1 = ep[i + 1];
        int e2 = ep[i + 2];
        int e3 = ep[i + 3];
        uint4 w0 = *(const uint4*)(base + e0 * ROWU);
        uint4 w1 = *(const uint4*)(base + e1 * ROWU);
        uint4 w2 = *(const uint4*)(base + e2 * ROWU);
        uint4 w3 = *(const uint4*)(base + e3 * ROWU);
        acc2(s[0], s[1], w0.x, sc); acc2(s[2], s[3], w0.y, sc);
        acc2(s[4], s[5], w0.z, sc); acc2(s[6], s[7], w0.w, sc);
        acc2(s[0], s[1], w1.x, sc); acc2(s[2], s[3], w1.y, sc);
        acc2(s[4], s[5], w1.z, sc); acc2(s[6], s[7], w1.w, sc);
        acc2(s[0], s[1], w2.x, sc); acc2(s[2], s[3], w2.y, sc);
        acc2(s[4], s[5], w2.z, sc); acc2(s[6], s[7], w2.w, sc);
        acc2(s[0], s[1], w3.x, sc); acc2(s[2], s[3], w3.y, sc);
        acc2(s[4], s[5], w3.z, sc); acc2(s[6], s[7], w3.w, sc);
    }
    for (int i = nfull; i < n; i++) {
        int e = ep[i];
        uint4 w = *(const uint4*)(base + e * ROWU);
        acc2(s[0], s[1], w.x, sc); acc2(s[2], s[3], w.y, sc);
        acc2(s[4], s[5], w.z, sc); acc2(s[6], s[7], w.w, sc);
    }
}

// ---------- fused layer-1 gather: 8-lane group per node, 64 feats ----------
__global__ __launch_bounds__(256) void k_gather64v5(
    const bf16* __restrict__ m1,
    const int* __restrict__ offA0, const unsigned short* __restrict__ eA0,
    const int* __restrict__ offB0, const unsigned short* __restrict__ eB0,
    const float* __restrict__ bias0, bf16* __restrict__ out0,
    const int* __restrict__ offA1, const unsigned short* __restrict__ eA1,
    const int* __restrict__ offB1, const unsigned short* __restrict__ eB1,
    const float* __restrict__ bias1, bf16* __restrict__ out1)
{
    int tid  = threadIdx.x;
    int gid  = blockIdx.x * 32 + (tid >> 3);   // grid exact: 3125*32 = 100000
    int lidx = tid & 7;
    int half = (gid >= N_NODE);
    int wid  = gid - (half ? N_NODE : 0);
    const int* offA = half ? offA1 : offA0;
    const unsigned short* eA = half ? eA1 : eA0;
    const int* offB = half ? offB1 : offB0;
    const unsigned short* eB = half ? eB1 : eB0;
    const float* bias = half ? bias1 : bias0;
    bf16* out = half ? out1 : out0;

    const unsigned* base = (const unsigned*)m1 + (half ? 32 : 0) + lidx * 4;

    int begA = offA[wid], nA = offA[wid + 1] - begA;
    int begB = offB[wid], nB = offB[wid + 1] - begB;
    float ia = 1.f / (float)max(nA, 1);
    float ib = 1.f / (float)max(nB, 1);

    float s[8] = {0.f,0.f,0.f,0.f,0.f,0.f,0.f,0.f};
    seg_run<64>(nA, eA + begA, ia, base, s);
    seg_run<64>(nB, eB + begB, ib, base + N_NODE * 64, s);

    float h[8];
#pragma unroll
    for (int k = 0; k < 8; k++)
        h[k] = fmaxf(s[k] + bias[lidx * 8 + k], 0.f);
    uint4 v;
    v.x = pk2(h[0], h[1]); v.y = pk2(h[2], h[3]);
    v.z = pk2(h[4], h[5]); v.w = pk2(h[6], h[7]);
    *(uint4*)(out + (size_t)wid * 64 + lidx * 8) = v;
}

// ---------- fused layer-2 gather: 4-lane group per node, 32 feats, f32 out ----------
__global__ __launch_bounds__(256) void k_gather32v2(
    const bf16* __restrict__ m2,
    const int* __restrict__ offA0, const unsigned short* __restrict__ eA0,
    const int* __restrict__ offB0, const unsigned short* __restrict__ eB0,
    const float* __restrict__ bias0, float* __restrict__ out0,
    const int* __restrict__ offA1, const unsigned short* __restrict__ eA1,
    const int* __restrict__ offB1, const unsigned short* __restrict__ eB1,
    const float* __restrict__ bias1, float* __restrict__ out1)
{
    int tid  = threadIdx.x;
    int gid  = blockIdx.x * 64 + (tid >> 2);
    int lidx = tid & 3;
    if (gid >= 2 * N_NODE) return;
    int half = (gid >= N_NODE);
    int wid  = gid - (half ? N_NODE : 0);
    const int* offA = half ? offA1 : offA0;
    const unsigned short* eA = half ? eA1 : eA0;
    const int* offB = half ? offB1 : offB0;
    const unsigned short* eB = half ? eB1 : eB0;
    const float* bias = half ? bias1 : bias0;
    float* out = half ? out1 : out0;

    const unsigned* base = (const unsigned*)m2 + (half ? 16 : 0) + lidx * 4;

    int begA = offA[wid], nA = offA[wid + 1] - begA;
    int begB = offB[wid], nB = offB[wid + 1] - begB;
    float ia = 1.f / (float)max(nA, 1);
    float ib = 1.f / (float)max(nB, 1);

    float s[8] = {0.f,0.f,0.f,0.f,0.f,0.f,0.f,0.f};
    seg_run<32>(nA, eA + begA, ia, base, s);
    seg_run<32>(nB, eB + begB, ib, base + N_NODE * 32, s);

    float* o = out + (size_t)wid * 32 + lidx * 8;
    float4 v0, v1;
    v0.x = s[0] + bias[lidx * 8 + 0];
    v0.y = s[1] + bias[lidx * 8 + 1];
    v0.z = s[2] + bias[lidx * 8 + 2];
    v0.w = s[3] + bias[lidx * 8 + 3];
    v1.x = s[4] + bias[lidx * 8 + 4];
    v1.y = s[5] + bias[lidx * 8 + 5];
    v1.z = s[6] + bias[lidx * 8 + 6];
    v1.w = s[7] + bias[lidx * 8 + 7];
    *(float4*)o = v0;
    *(float4*)(o + 4) = v1;
}

// ---------------- launcher ----------------
extern "C" void kernel_launch(void* const* d_in, const int* in_sizes, int n_in,
                              void* d_out, int out_size, void* d_ws, size_t ws_size,
                              hipStream_t stream)
{
    const float* xd = (const float*)d_in[0];
    const float* xg = (const float*)d_in[1];
    const int* dd_src = (const int*)d_in[2];  const int* dd_dst = (const int*)d_in[3];
    const int* dg_src = (const int*)d_in[4];  const int* dg_dst = (const int*)d_in[5];
    const int* gd_src = (const int*)d_in[6];  const int* gd_dst = (const int*)d_in[7];
    const int* gg_src = (const int*)d_in[8];  const int* gg_dst = (const int*)d_in[9];
    const float* W1dd = (const float*)d_in[10];
    const float* W1dg = (const float*)d_in[11];
    const float* W1gd = (const float*)d_in[12];
    const float* W1gg = (const float*)d_in[13];
    const float* b1d  = (const float*)d_in[14];
    const float* b1g  = (const float*)d_in[15];
    const float* W2dd = (const float*)d_in[16];
    const float* W2dg = (const float*)d_in[17];
    const float* W2gd = (const float*)d_in[18];
    const float* W2gg = (const float*)d_in[19];
    const float* b2d  = (const float*)d_in[20];
    const float* b2g  = (const float*)d_in[21];
    float* out = (float*)d_out;

    // workspace layout (vector-accessed regions 16B-aligned)
    int* gcur     = (int*)d_ws;                        // 512 ints
    int* off      = gcur + 512;                        // 4*(N_NODE+1) = 200004
    unsigned short* edges = (unsigned short*)(off + 4 * (N_NODE + 1));  // 4*NEDGE u16 (4.8 MB)
    bf16* md1     = (bf16*)(edges + (size_t)4 * NEDGE);// [md1|mg1]: 2*50000*128 bf16 (25.6 MB)
    bf16* mg1     = md1 + (size_t)N_NODE * 128;
    bf16* h       = mg1 + (size_t)N_NODE * 128;        // [hd|hg]: 2*50000*64 bf16 (12.8 MB)
    bf16* hd      = h;
    bf16* hg      = h + (size_t)N_NODE * 64;
    bf16* md2     = md1;                               // layer-2 out packed (stride 64 bf16)
    bf16* mg2     = md1 + (size_t)N_NODE * 64;         // B-row i = row (i + N_NODE)
    unsigned* gpart = (unsigned*)h;                    // 512*CAPB uints (12.58 MB) aliases h:
                                                       // dead after k_csr, before gather64 writes h.
                                                       // (md1 must NOT alias gpart: GEMM runs || part.)

    // ---- stage 1: edge partition || layer-1 GEMM (688 blocks -> single scheduling round) ----
    hipMemsetAsync(gcur, 0, 512 * sizeof(int), stream);
    k_part_gemm<<<4 * NBLK1 + 2 * GEMM_GB, 512, 0, stream>>>(
        dd_dst, dd_src, gd_dst, gd_src, dg_dst, dg_src, gg_dst, gg_src, gcur, gpart,
        xd, xg, W1dd, W1dg, W1gd, W1gg, md1, mg1);

    // ---- stage 2: CSR finalize ----
    k_csr<<<512, 512, 0, stream>>>(gpart, gcur, off, edges);

    const int* off_dd = off + 0 * (N_NODE + 1);
    const int* off_gd = off + 1 * (N_NODE + 1);
    const int* off_dg = off + 2 * (N_NODE + 1);
    const int* off_gg = off + 3 * (N_NODE + 1);
    const unsigned short* e_dd = edges + (size_t)0 * NEDGE;
    const unsigned short* e_gd = edges + (size_t)1 * NEDGE;
    const unsigned short* e_dg = edges + (size_t)2 * NEDGE;
    const unsigned short* e_gg = edges + (size_t)3 * NEDGE;

    int g64_grid = (2 * N_NODE) / 32;          // 3125 blocks exact
    int g32_grid = (2 * N_NODE + 63) / 64;     // 1563 blocks
    dim3 gemm2_grid((N_NODE + 63) / 64, 2);

    // ---- stage 3: layer-1 gather -> h ----
    k_gather64v5<<<g64_grid, 256, 0, stream>>>(
        md1,
        off_dd, e_dd, off_gd, e_gd, b1d, hd,
        off_dg, e_dg, off_gg, e_gg, b1g, hg);

    // ---- stage 4: layer-2 GEMM (md1 region is dead now) ----
    k_gemm_pair<64, 64, false><<<gemm2_grid, 256, 0, stream>>>(
        hd, hg, W2dd, W2dg, W2gd, W2gg, md2, mg2, N_NODE);

    // ---- stage 5: layer-2 gather -> out ----
    k_gather32v2<<<g32_grid, 256, 0, stream>>>(
        md2,
        off_dd, e_dd, off_gd, e_gd, b2d, out,
        off_dg, e_dg, off_gg, e_gg, b2g, out + (size_t)N_NODE * 32);
}